// Round 1
// 337.386 us; speedup vs baseline: 1.0029x; 1.0029x over previous
//
#include <hip/hip_runtime.h>

// Problem constants (fixed by the reference: shape (20,1,128,128,128) fp32)
#define NBATCH 20
#define ELEMS_PER_BATCH (128 * 128 * 128)       // 2,097,152
#define BLOCKS_PER_BATCH 64                     // 1280 blocks = 5120 waves = 20/CU, single dispatch round
#define THREADS 256
#define BAT 4                                   // float4-pairs per pipeline batch (8 loads in flight)
#define NSTEP 8                                 // BAT*NSTEP*THREADS*4 = 32768 elems/block * 64 = 2,097,152
#define NPART (NBATCH * BLOCKS_PER_BATCH)       // 1280 partials

#define LN2 0.69314718055994530942
// torch clamps log at -100 -> in log2 space: -100/ln2
#define LOG2_CLAMP (-144.26950408889634f)

// Load one batch of BAT float4 pairs. Kept as a forced-inline helper so every
// array index is compile-time constant (stays in VGPRs, never scratch).
__device__ __forceinline__ void load_batch(const float4* __restrict__ x4,
                                           const float4* __restrict__ y4,
                                           long base, int tid,
                                           float4 (&bx)[BAT], float4 (&by)[BAT]) {
#pragma unroll
  for (int j = 0; j < BAT; ++j) {
    const long idx = base + (long)j * THREADS + tid;
    bx[j] = x4[idx];
    by[j] = y4[idx];
  }
}

__device__ __forceinline__ void compute_batch(const float4 (&bx)[BAT],
                                              const float4 (&by)[BAT],
                                              float& bce2, int& pc, int& tc) {
#pragma unroll
  for (int j = 0; j < BAT; ++j) {
#pragma unroll
    for (int c = 0; c < 4; ++c) {
      const float xx = (c == 0) ? bx[j].x : (c == 1) ? bx[j].y : (c == 2) ? bx[j].z : bx[j].w;
      const float yy = (c == 0) ? by[j].x : (c == 1) ? by[j].y : (c == 2) ? by[j].z : by[j].w;
      // BCE in log2 space via hardware v_log_f32 (Round-1 win: libm logf was
      // VALU-bound). log1p(-x) -> log2(1-x): exact for x>=0.5 (Sterbenz).
      const float lx = fmaxf(__builtin_amdgcn_logf(xx),        LOG2_CLAMP);
      const float l1 = fmaxf(__builtin_amdgcn_logf(1.0f - xx), LOG2_CLAMP);
      // y*lx + (1-y)*l1 = l1 + y*(lx - l1)
      bce2 += l1 + yy * (lx - l1);
      pc += (xx <= 0.5f);
      tc += (yy < 1.0f);
    }
  }
}

// Kernel 1: per-block partial reductions.
// Round-2 restructure: ping-pong register double-buffer. Old version had
// VGPR_Count=24 -> compiler emitted load;load;waitcnt(0);compute with ~2
// outstanding loads/wave -> latency-bound at 2.8 TB/s consumption with
// VALUBusy 12.6%. Here batch s+1's 8 loads are issued before computing
// batch s, keeping 8 x 1 KiB wave-loads in flight.
__global__ __launch_bounds__(THREADS) void partial_kernel(
    const float* __restrict__ x, const float* __restrict__ y,
    float* __restrict__ bce_part, int* __restrict__ pred_part,
    int* __restrict__ true_part) {
  const int b   = blockIdx.y;
  const int seg = blockIdx.x;
  const int tid = threadIdx.x;

  const long base4 = (long)b * (ELEMS_PER_BATCH / 4) +
                     (long)seg * (BAT * NSTEP * THREADS);
  const float4* __restrict__ x4 = (const float4*)x;
  const float4* __restrict__ y4 = (const float4*)y;

  float bce2 = 0.0f;  // sum in log2 units
  int pc = 0, tc = 0;

  float4 ax[BAT], ay[BAT], bx[BAT], by[BAT];
  load_batch(x4, y4, base4, tid, ax, ay);

  // Manually unrolled ping-pong so buffer selection is compile-time (no
  // runtime-indexed arrays -> no scratch spill, rule #20).
#define PIPE_STEP(CX, CY, NX, NY, S)                                           \
  if ((S) + 1 < NSTEP)                                                         \
    load_batch(x4, y4, base4 + (long)((S) + 1) * (BAT * THREADS), tid, NX, NY);\
  compute_batch(CX, CY, bce2, pc, tc);

  PIPE_STEP(ax, ay, bx, by, 0)
  PIPE_STEP(bx, by, ax, ay, 1)
  PIPE_STEP(ax, ay, bx, by, 2)
  PIPE_STEP(bx, by, ax, ay, 3)
  PIPE_STEP(ax, ay, bx, by, 4)
  PIPE_STEP(bx, by, ax, ay, 5)
  PIPE_STEP(ax, ay, bx, by, 6)
  PIPE_STEP(bx, by, ax, ay, 7)
#undef PIPE_STEP

  __shared__ float sb[THREADS];
  __shared__ int   sp[THREADS];
  __shared__ int   st[THREADS];
  sb[tid] = bce2; sp[tid] = pc; st[tid] = tc;
  __syncthreads();
#pragma unroll
  for (int s = THREADS / 2; s > 0; s >>= 1) {
    if (tid < s) {
      sb[tid] += sb[tid + s];
      sp[tid] += sp[tid + s];
      st[tid] += st[tid + s];
    }
    __syncthreads();
  }
  if (tid == 0) {
    const int o = b * BLOCKS_PER_BATCH + seg;
    bce_part[o]  = (float)(sb[0] * LN2);  // back to natural-log units
    pred_part[o] = sp[0];
    true_part[o] = st[0];
  }
}

// Kernel 2: single block. Double-precision BCE total; per-batch POR; compose.
__global__ __launch_bounds__(THREADS) void final_kernel(
    const float* __restrict__ bce_part, const int* __restrict__ pred_part,
    const int* __restrict__ true_part, float* __restrict__ out) {
  const int tid = threadIdx.x;
  __shared__ double sred[THREADS];
  __shared__ float  spor[NBATCH];

  double local = 0.0;
  for (int i = tid; i < NPART; i += THREADS) local += (double)bce_part[i];
  sred[tid] = local;
  __syncthreads();
#pragma unroll
  for (int s = THREADS / 2; s > 0; s >>= 1) {
    if (tid < s) sred[tid] += sred[tid + s];
    __syncthreads();
  }

  if (tid < NBATCH) {
    int pc = 0, tc = 0;
    for (int k = 0; k < BLOCKS_PER_BATCH; ++k) {
      pc += pred_part[tid * BLOCKS_PER_BATCH + k];
      tc += true_part[tid * BLOCKS_PER_BATCH + k];
    }
    const float pp = (float)pc / (float)ELEMS_PER_BATCH;
    const float pt = (float)tc / (float)ELEMS_PER_BATCH;
    const float d = pp - pt;
    spor[tid] = d * d;
  }
  __syncthreads();

  if (tid == 0) {
    float pore_sum = 0.0f;
#pragma unroll
    for (int b = 0; b < NBATCH; ++b) pore_sum += spor[b];
    const float pore = pore_sum / (float)NBATCH;
    const double total = (double)NBATCH * (double)ELEMS_PER_BATCH;
    const float mse = (float)(-(sred[0] / total));
    out[0] = pore + mse;
    out[1] = pore;
  }
}

extern "C" void kernel_launch(void* const* d_in, const int* in_sizes, int n_in,
                              void* d_out, int out_size, void* d_ws, size_t ws_size,
                              hipStream_t stream) {
  const float* x = (const float*)d_in[0];
  const float* y = (const float*)d_in[1];
  float* out = (float*)d_out;

  // Workspace layout: [NPART floats][NPART ints][NPART ints] — every slot is
  // fully overwritten by partial_kernel, so no init needed despite 0xAA poison.
  float* bce_part  = (float*)d_ws;
  int*   pred_part = (int*)(bce_part + NPART);
  int*   true_part = pred_part + NPART;

  dim3 grid(BLOCKS_PER_BATCH, NBATCH);
  partial_kernel<<<grid, THREADS, 0, stream>>>(x, y, bce_part, pred_part, true_part);
  final_kernel<<<1, THREADS, 0, stream>>>(bce_part, pred_part, true_part, out);
}

// Round 3
// 304.737 us; speedup vs baseline: 1.1104x; 1.1071x over previous
//
#include <hip/hip_runtime.h>

// Problem constants (fixed by the reference: shape (20,1,128,128,128) fp32)
#define NBATCH 20
#define ELEMS_PER_BATCH (128 * 128 * 128)       // 2,097,152
#define BLOCKS_PER_BATCH 64                     // 1280 blocks = 5120 waves = 20/CU, single dispatch round
#define THREADS 256
#define BAT 4                                   // float4-pairs per pipeline batch
#define NSTEP 8                                 // BAT*NSTEP*THREADS*4 = 32768 elems/block * 64 = 2,097,152
#define NPART (NBATCH * BLOCKS_PER_BATCH)       // 1280 partials

#define LN2 0.69314718055994530942
// torch clamps log at -100 -> in log2 space: -100/ln2
#define LOG2_CLAMP (-144.26950408889634f)

// Native clang vector type: __builtin_nontemporal_load requires a pointer to
// scalar/vector-of-scalar, not HIP_vector_type (Round-2 compile failure).
typedef float f4 __attribute__((ext_vector_type(4)));

// Round-3 experiment (retry of R2): NON-TEMPORAL loads (nt cache policy,
// bypass L2/L3 retention). R0/R1 both plateaued at 2.84 TB/s effective read
// BW with HBM serving exactly half (1.42 TB/s, 18% peak) and L3 the other
// half — while VALUBusy=12.7% and bandwidth-delay arithmetic shows MLP is
// NOT the limit (~0.16 KB/wave in flight suffices for 6.3 TB/s; we have
// ~10x that; requests queue ~9k cycles). Theory: the mixed L3-hit/miss
// service path is the ~2.84 TB/s cap. x,y are read exactly once (zero
// reuse), so bypassing cache retention costs nothing and pure HBM streams
// should run at the HBM read ceiling.
__device__ __forceinline__ void load_batch(const f4* __restrict__ x4,
                                           const f4* __restrict__ y4,
                                           long base, int tid,
                                           f4 (&bx)[BAT], f4 (&by)[BAT]) {
#pragma unroll
  for (int j = 0; j < BAT; ++j) {
    const long idx = base + (long)j * THREADS + tid;
    bx[j] = __builtin_nontemporal_load(&x4[idx]);
    by[j] = __builtin_nontemporal_load(&y4[idx]);
  }
}

__device__ __forceinline__ void compute_batch(const f4 (&bx)[BAT],
                                              const f4 (&by)[BAT],
                                              float& bce2, int& pc, int& tc) {
#pragma unroll
  for (int j = 0; j < BAT; ++j) {
#pragma unroll
    for (int c = 0; c < 4; ++c) {
      const float xx = bx[j][c];
      const float yy = by[j][c];
      // BCE in log2 space via hardware v_log_f32 (libm logf was VALU-bound).
      // log1p(-x) -> log2(1-x): exact for x>=0.5 (Sterbenz).
      const float lx = fmaxf(__builtin_amdgcn_logf(xx),        LOG2_CLAMP);
      const float l1 = fmaxf(__builtin_amdgcn_logf(1.0f - xx), LOG2_CLAMP);
      // y*lx + (1-y)*l1 = l1 + y*(lx - l1)
      bce2 += l1 + yy * (lx - l1);
      pc += (xx <= 0.5f);
      tc += (yy < 1.0f);
    }
  }
}

// Kernel 1: per-block partial reductions.
__global__ __launch_bounds__(THREADS) void partial_kernel(
    const float* __restrict__ x, const float* __restrict__ y,
    float* __restrict__ bce_part, int* __restrict__ pred_part,
    int* __restrict__ true_part) {
  const int b   = blockIdx.y;
  const int seg = blockIdx.x;
  const int tid = threadIdx.x;

  const long base4 = (long)b * (ELEMS_PER_BATCH / 4) +
                     (long)seg * (BAT * NSTEP * THREADS);
  const f4* __restrict__ x4 = (const f4*)x;
  const f4* __restrict__ y4 = (const f4*)y;

  float bce2 = 0.0f;  // sum in log2 units
  int pc = 0, tc = 0;

  f4 ax[BAT], ay[BAT], bx[BAT], by[BAT];
  load_batch(x4, y4, base4, tid, ax, ay);

  // Ping-pong register double-buffer; buffer selection compile-time (rule #20).
#define PIPE_STEP(CX, CY, NX, NY, S)                                           \
  if ((S) + 1 < NSTEP)                                                         \
    load_batch(x4, y4, base4 + (long)((S) + 1) * (BAT * THREADS), tid, NX, NY);\
  compute_batch(CX, CY, bce2, pc, tc);

  PIPE_STEP(ax, ay, bx, by, 0)
  PIPE_STEP(bx, by, ax, ay, 1)
  PIPE_STEP(ax, ay, bx, by, 2)
  PIPE_STEP(bx, by, ax, ay, 3)
  PIPE_STEP(ax, ay, bx, by, 4)
  PIPE_STEP(bx, by, ax, ay, 5)
  PIPE_STEP(ax, ay, bx, by, 6)
  PIPE_STEP(bx, by, ax, ay, 7)
#undef PIPE_STEP

  __shared__ float sb[THREADS];
  __shared__ int   sp[THREADS];
  __shared__ int   st[THREADS];
  sb[tid] = bce2; sp[tid] = pc; st[tid] = tc;
  __syncthreads();
#pragma unroll
  for (int s = THREADS / 2; s > 0; s >>= 1) {
    if (tid < s) {
      sb[tid] += sb[tid + s];
      sp[tid] += sp[tid + s];
      st[tid] += st[tid + s];
    }
    __syncthreads();
  }
  if (tid == 0) {
    const int o = b * BLOCKS_PER_BATCH + seg;
    bce_part[o]  = (float)(sb[0] * LN2);  // back to natural-log units
    pred_part[o] = sp[0];
    true_part[o] = st[0];
  }
}

// Kernel 2: single block. Double-precision BCE total; per-batch POR; compose.
__global__ __launch_bounds__(THREADS) void final_kernel(
    const float* __restrict__ bce_part, const int* __restrict__ pred_part,
    const int* __restrict__ true_part, float* __restrict__ out) {
  const int tid = threadIdx.x;
  __shared__ double sred[THREADS];
  __shared__ float  spor[NBATCH];

  double local = 0.0;
  for (int i = tid; i < NPART; i += THREADS) local += (double)bce_part[i];
  sred[tid] = local;
  __syncthreads();
#pragma unroll
  for (int s = THREADS / 2; s > 0; s >>= 1) {
    if (tid < s) sred[tid] += sred[tid + s];
    __syncthreads();
  }

  if (tid < NBATCH) {
    int pc = 0, tc = 0;
    for (int k = 0; k < BLOCKS_PER_BATCH; ++k) {
      pc += pred_part[tid * BLOCKS_PER_BATCH + k];
      tc += true_part[tid * BLOCKS_PER_BATCH + k];
    }
    const float pp = (float)pc / (float)ELEMS_PER_BATCH;
    const float pt = (float)tc / (float)ELEMS_PER_BATCH;
    const float d = pp - pt;
    spor[tid] = d * d;
  }
  __syncthreads();

  if (tid == 0) {
    float pore_sum = 0.0f;
#pragma unroll
    for (int b = 0; b < NBATCH; ++b) pore_sum += spor[b];
    const float pore = pore_sum / (float)NBATCH;
    const double total = (double)NBATCH * (double)ELEMS_PER_BATCH;
    const float mse = (float)(-(sred[0] / total));
    out[0] = pore + mse;
    out[1] = pore;
  }
}

extern "C" void kernel_launch(void* const* d_in, const int* in_sizes, int n_in,
                              void* d_out, int out_size, void* d_ws, size_t ws_size,
                              hipStream_t stream) {
  const float* x = (const float*)d_in[0];
  const float* y = (const float*)d_in[1];
  float* out = (float*)d_out;

  // Workspace layout: [NPART floats][NPART ints][NPART ints] — every slot is
  // fully overwritten by partial_kernel, so no init needed despite 0xAA poison.
  float* bce_part  = (float*)d_ws;
  int*   pred_part = (int*)(bce_part + NPART);
  int*   true_part = pred_part + NPART;

  dim3 grid(BLOCKS_PER_BATCH, NBATCH);
  partial_kernel<<<grid, THREADS, 0, stream>>>(x, y, bce_part, pred_part, true_part);
  final_kernel<<<1, THREADS, 0, stream>>>(bce_part, pred_part, true_part, out);
}